// Round 2
// baseline (225.821 us; speedup 1.0000x reference)
//
#include <hip/hip_runtime.h>

// QuantumKernelMethod: analytic collapse.
// The circuit = (permutation ∘ diagonal-phase)^4 applied to a REAL product
// state. The permutation and phases depend only on params (shared by the X
// and Y states), so they cancel in <psi_x|psi_y>:
//   M[x,y] = prod_i cos((x_i - y_i)/2)
//          = prod_i [cos(x_i/2)cos(y_i/2) + sin(x_i/2)sin(y_i/2)]
//   out    = M^2.
// params is provably unused. Pure store-BW-bound: 64 MB fp32 output.
//
// Single fused kernel: each block covers 16 rows x 1024 cols.
//  - row (cos,sin) staged in LDS by the first 160 threads (broadcast reads
//    in the main loop: all lanes same address -> conflict-free).
//  - each thread holds 4 columns' (cos,sin) for all 10 wires in registers.

#define NS 4096   // samples per set
#define NW 10     // wires
#define ROWS 16   // rows per block

__global__ __launch_bounds__(256, 4) void qkm_fused(
    const float* __restrict__ X, const float* __restrict__ Y,
    float* __restrict__ out) {
    __shared__ float2 xcs[ROWS][NW];                    // 1.25 KB

    const int col  = (blockIdx.x * 256 + threadIdx.x) * 4;  // 4 cols/thread
    const int row0 = blockIdx.y * ROWS;

    // Stage this block's 16 rows of X half-angle (cos,sin) into LDS.
    if (threadIdx.x < ROWS * NW) {
        int r = threadIdx.x / NW;
        int w = threadIdx.x - r * NW;
        float s, c;
        __sincosf(0.5f * X[(row0 + r) * NW + w], &s, &c);
        xcs[r][w] = make_float2(c, s);
    }

    // This thread's 4 columns: (cos,sin) of Y half-angles, in registers.
    float yc[NW][4], ys[NW][4];
#pragma unroll
    for (int j = 0; j < 4; ++j) {
        const float* yp = Y + (size_t)(col + j) * NW;   // 10 contiguous floats
#pragma unroll
        for (int w = 0; w < NW; ++w) {
            float s, c;
            __sincosf(0.5f * yp[w], &s, &c);
            yc[w][j] = c;
            ys[w][j] = s;
        }
    }

    __syncthreads();

#pragma unroll 4
    for (int r = 0; r < ROWS; ++r) {
        float p0 = 1.f, p1 = 1.f, p2 = 1.f, p3 = 1.f;
#pragma unroll
        for (int w = 0; w < NW; ++w) {
            const float2 x = xcs[r][w];                 // LDS broadcast
            p0 *= fmaf(x.y, ys[w][0], x.x * yc[w][0]);
            p1 *= fmaf(x.y, ys[w][1], x.x * yc[w][1]);
            p2 *= fmaf(x.y, ys[w][2], x.x * yc[w][2]);
            p3 *= fmaf(x.y, ys[w][3], x.x * yc[w][3]);
        }
        float4 o;
        o.x = p0 * p0; o.y = p1 * p1; o.z = p2 * p2; o.w = p3 * p3;
        *reinterpret_cast<float4*>(out + (size_t)(row0 + r) * NS + col) = o;
    }
}

extern "C" void kernel_launch(void* const* d_in, const int* in_sizes, int n_in,
                              void* d_out, int out_size, void* d_ws, size_t ws_size,
                              hipStream_t stream) {
    const float* X = (const float*)d_in[0];   // (4096, 10)
    const float* Y = (const float*)d_in[1];   // (4096, 10)
    // d_in[2] = params (4,10): unused (phases cancel in |<x|y>|^2).
    float* out = (float*)d_out;               // (4096, 4096) fp32

    dim3 grid(NS / (256 * 4), NS / ROWS);     // (4, 256)
    qkm_fused<<<grid, 256, 0, stream>>>(X, Y, out);
}

// Round 3
// 89.362 us; speedup vs baseline: 2.5270x; 2.5270x over previous
//
#include <hip/hip_runtime.h>

// QuantumKernelMethod: analytic collapse.
// The circuit = (permutation ∘ diagonal-phase)^4 applied to a REAL product
// state. The permutation and phases depend only on params (shared by the X
// and Y states), so they cancel in <psi_x|psi_y>:
//   M[x,y] = prod_i cos((x_i - y_i)/2)
//          = prod_i [cos(x_i/2)cos(y_i/2) + sin(x_i/2)sin(y_i/2)]
//   out    = M^2.
// params is provably unused. Pure store-BW-bound: 64 MB fp32 output.
//
// R2 lesson: __launch_bounds__(256,4) + 80-float/thread arrays => VGPR cap
// 128 => spill => 374 MB scratch fetch. Fix: 2 cols/thread (40 VGPRs of
// y-data), NO min-waves bound. Block covers 32 rows x 512 cols.

#define NS 4096   // samples per set
#define NW 10     // wires
#define ROWS 32   // rows per block
#define CPT 2     // columns per thread

__global__ __launch_bounds__(256) void qkm_fused(
    const float* __restrict__ X, const float* __restrict__ Y,
    float* __restrict__ out) {
    __shared__ float2 xcs[ROWS][NW];                    // 2.5 KB

    const int col  = (blockIdx.x * 256 + threadIdx.x) * CPT;
    const int row0 = blockIdx.y * ROWS;

    // Stage this block's 32 rows of X half-angle (cos,sin) into LDS.
    for (int t = threadIdx.x; t < ROWS * NW; t += 256) {
        int r = t / NW;
        int w = t - r * NW;
        float s, c;
        __sincosf(0.5f * X[(row0 + r) * NW + w], &s, &c);
        xcs[r][w] = make_float2(c, s);
    }

    // This thread's 2 columns: (cos,sin) of Y half-angles, in registers.
    float yc[NW][CPT], ys[NW][CPT];
#pragma unroll
    for (int j = 0; j < CPT; ++j) {
        const float* yp = Y + (size_t)(col + j) * NW;   // 10 contiguous floats
#pragma unroll
        for (int w = 0; w < NW; ++w) {
            float s, c;
            __sincosf(0.5f * yp[w], &s, &c);
            yc[w][j] = c;
            ys[w][j] = s;
        }
    }

    __syncthreads();

#pragma unroll 4
    for (int r = 0; r < ROWS; ++r) {
        float p0 = 1.f, p1 = 1.f;
#pragma unroll
        for (int w = 0; w < NW; ++w) {
            const float2 x = xcs[r][w];                 // LDS broadcast (free)
            p0 *= fmaf(x.y, ys[w][0], x.x * yc[w][0]);
            p1 *= fmaf(x.y, ys[w][1], x.x * yc[w][1]);
        }
        float2 o;
        o.x = p0 * p0;
        o.y = p1 * p1;
        *reinterpret_cast<float2*>(out + (size_t)(row0 + r) * NS + col) = o;
    }
}

extern "C" void kernel_launch(void* const* d_in, const int* in_sizes, int n_in,
                              void* d_out, int out_size, void* d_ws, size_t ws_size,
                              hipStream_t stream) {
    const float* X = (const float*)d_in[0];   // (4096, 10)
    const float* Y = (const float*)d_in[1];   // (4096, 10)
    // d_in[2] = params (4,10): unused (phases cancel in |<x|y>|^2).
    float* out = (float*)d_out;               // (4096, 4096) fp32

    dim3 grid(NS / (256 * CPT), NS / ROWS);   // (8, 128)
    qkm_fused<<<grid, 256, 0, stream>>>(X, Y, out);
}

// Round 5
// 82.955 us; speedup vs baseline: 2.7222x; 1.0772x over previous
//
#include <hip/hip_runtime.h>

// QuantumKernelMethod: analytic collapse.
//   out[x,y] = M^2,  M = prod_i cos((x_i - y_i)/2)
//            = prod_i [cos(x_i/2)cos(y_i/2) + sin(x_i/2)sin(y_i/2)]
// (params provably unused: the RZ phases / CNOT permutation are sample-
// independent and cancel in |<psi_x|psi_y>|^2.)
//
// R3 lesson: dot-form inner loop = 3 VALU/wire/col => ~27 us VALU-bound.
// R4 lesson: staging guard `tid < 320` with 256 threads left rows 25..31
//            unstaged => garbage. Fix: strided staging loop (as in R3).
// Math: tan factoring  M = Cx * prod_i (cy_i + tx_i * sy_i)  (fma/wire),
//       packed f32 pair (ext_vector_type(2) -> v_pk_fma_f32) => ~1 inst
//       per wire for BOTH columns. Row record [tx0..9, Cx, pad]: 3x b128.

#define NS 4096   // samples per set
#define NW 10     // wires
#define ROWS 32   // rows per block
#define CPT 2     // columns per thread (packed pair)

typedef float v2f __attribute__((ext_vector_type(2)));

static __device__ inline v2f splat2(float x) { v2f v; v.x = x; v.y = x; return v; }

__global__ __launch_bounds__(256) void qkm_fused(
    const float* __restrict__ X, const float* __restrict__ Y,
    float* __restrict__ out) {
    __shared__ float xrow[ROWS][12];   // per row: tx[0..9], Cx, pad (48 B, 16B-aligned)
    __shared__ float cxa[ROWS][NW];    // staging for the Cx product reduce

    const int col  = (blockIdx.x * 256 + threadIdx.x) * CPT;
    const int row0 = blockIdx.y * ROWS;

    // Stage per-(row,wire): tan(x/2) and cos(x/2).  ROWS*NW=320 > 256 threads
    // => MUST stride (R4 bug: plain `if` left rows 25..31 unstaged).
    for (int t = threadIdx.x; t < ROWS * NW; t += 256) {
        int r = t / NW;
        int w = t - r * NW;
        float s, c;
        __sincosf(0.5f * X[(row0 + r) * NW + w], &s, &c);
        // |cos(x/2)| >= ~4e-8 for representable x in [0,2pi]; guard anyway.
        float cs = (fabsf(c) < 1e-30f) ? copysignf(1e-30f, c) : c;
        xrow[r][w] = __fdividef(s, cs);   // tx = tan(x/2)
        cxa[r][w]  = cs;
    }

    // This thread's 2 columns: (cos,sin) of Y half-angles in packed regs.
    v2f cy[NW], sy[NW];
#pragma unroll
    for (int w = 0; w < NW; ++w) {
        float s0, c0, s1, c1;
        __sincosf(0.5f * Y[(size_t)col * NW + w], &s0, &c0);
        __sincosf(0.5f * Y[(size_t)(col + 1) * NW + w], &s1, &c1);
        v2f c; c.x = c0; c.y = c1;
        v2f s; s.x = s0; s.y = s1;
        cy[w] = c; sy[w] = s;
    }

    __syncthreads();
    if (threadIdx.x < ROWS) {                 // Cx = prod_i cos(x_i/2)
        int r = threadIdx.x;
        float p = cxa[r][0];
#pragma unroll
        for (int w = 1; w < NW; ++w) p *= cxa[r][w];
        xrow[r][NW] = p;
    }
    __syncthreads();

#pragma unroll 4
    for (int r = 0; r < ROWS; ++r) {
        float a[12];                          // tx[0..9], Cx  (3x ds_read_b128)
        *reinterpret_cast<float4*>(&a[0]) = *reinterpret_cast<const float4*>(&xrow[r][0]);
        *reinterpret_cast<float4*>(&a[4]) = *reinterpret_cast<const float4*>(&xrow[r][4]);
        *reinterpret_cast<float4*>(&a[8]) = *reinterpret_cast<const float4*>(&xrow[r][8]);
        v2f p = splat2(a[NW]);                // start from Cx
#pragma unroll
        for (int w = 0; w < NW; ++w)
            p = p * (cy[w] + splat2(a[w]) * sy[w]);   // v_pk_fma + v_pk_mul
        v2f o = p * p;
        *reinterpret_cast<v2f*>(out + (size_t)(row0 + r) * NS + col) = o;
    }
}

extern "C" void kernel_launch(void* const* d_in, const int* in_sizes, int n_in,
                              void* d_out, int out_size, void* d_ws, size_t ws_size,
                              hipStream_t stream) {
    const float* X = (const float*)d_in[0];   // (4096, 10)
    const float* Y = (const float*)d_in[1];   // (4096, 10)
    // d_in[2] = params (4,10): unused (phases cancel in |<x|y>|^2).
    float* out = (float*)d_out;               // (4096, 4096) fp32

    dim3 grid(NS / (256 * CPT), NS / ROWS);   // (8, 128)
    qkm_fused<<<grid, 256, 0, stream>>>(X, Y, out);
}